// Round 18
// baseline (32.526 us; speedup 1.0000x reference)
//
#include <hip/hip_runtime.h>

#define H     128
#define W     128
#define HO    126
#define WO    126
#define NPIX  (HO * WO)      // 15876
#define LW    128            // LDS row stride
#define BROWS 18             // staged rows per chunk buffer
#define BSZ   (BROWS * LW + 8)

// |d|-sum, threshold, tap count: 28 hand-scheduled VALU instrs.
// (Asm ONLY here: the compiler's compare/count codegen is fat; its FP-chain
// scheduling elsewhere is good -- R17 showed asm epi/max3 regresses.)
// Center tap contributes (0 >= thr) === (0 >= sad).
static __device__ __forceinline__ float count9(float d0, float d1, float d2, float d3,
                                               float d4, float d5, float d6, float d7) {
    float t0, t1, t2, t3, t4, t5, sad, thr, cnt, bvf;
    asm("v_add_f32 %[t0], |%[d0]|, |%[d1]|\n\t"
        "v_add_f32 %[t1], |%[d2]|, |%[d3]|\n\t"
        "v_add_f32 %[t2], |%[d4]|, |%[d5]|\n\t"
        "v_add_f32 %[t3], |%[d6]|, |%[d7]|\n\t"
        "v_add_f32 %[t4], %[t0], %[t1]\n\t"
        "v_add_f32 %[t5], %[t2], %[t3]\n\t"
        "v_add_f32 %[sad], %[t4], %[t5]\n\t"
        "v_mul_f32 %[thr], 0x3de38e39, %[sad]\n\t"   // * 1/9
        "v_mov_b32 %[cnt], 0\n\t"
        "v_cmp_ge_f32 vcc, 0, %[sad]\n\t"
        "v_addc_co_u32 %[cnt], vcc, 0, %[cnt], vcc\n\t"
        "v_cmp_ge_f32 vcc, %[d0], %[thr]\n\t"
        "v_addc_co_u32 %[cnt], vcc, 0, %[cnt], vcc\n\t"
        "v_cmp_ge_f32 vcc, %[d1], %[thr]\n\t"
        "v_addc_co_u32 %[cnt], vcc, 0, %[cnt], vcc\n\t"
        "v_cmp_ge_f32 vcc, %[d2], %[thr]\n\t"
        "v_addc_co_u32 %[cnt], vcc, 0, %[cnt], vcc\n\t"
        "v_cmp_ge_f32 vcc, %[d3], %[thr]\n\t"
        "v_addc_co_u32 %[cnt], vcc, 0, %[cnt], vcc\n\t"
        "v_cmp_ge_f32 vcc, %[d4], %[thr]\n\t"
        "v_addc_co_u32 %[cnt], vcc, 0, %[cnt], vcc\n\t"
        "v_cmp_ge_f32 vcc, %[d5], %[thr]\n\t"
        "v_addc_co_u32 %[cnt], vcc, 0, %[cnt], vcc\n\t"
        "v_cmp_ge_f32 vcc, %[d6], %[thr]\n\t"
        "v_addc_co_u32 %[cnt], vcc, 0, %[cnt], vcc\n\t"
        "v_cmp_ge_f32 vcc, %[d7], %[thr]\n\t"
        "v_addc_co_u32 %[cnt], vcc, 0, %[cnt], vcc\n\t"
        "v_cvt_f32_u32 %[bvf], %[cnt]"
        : [t0]"=&v"(t0), [t1]"=&v"(t1), [t2]"=&v"(t2), [t3]"=&v"(t3),
          [t4]"=&v"(t4), [t5]"=&v"(t5), [sad]"=&v"(sad), [thr]"=&v"(thr),
          [cnt]"=&v"(cnt), [bvf]"=v"(bvf)
        : [d0]"v"(d0), [d1]"v"(d1), [d2]"v"(d2), [d3]"v"(d3),
          [d4]"v"(d4), [d5]"v"(d5), [d6]"v"(d6), [d7]"v"(d7)
        : "vcc");
    return bvf;
}

// 8-px group: rows y..y+2, cols x0..x0+9. px 0..5 always valid; 6,7 iff full.
static __device__ __forceinline__ float grp8(const float* __restrict__ base, bool full) {
    float r[3][10];
#pragma unroll
    for (int i = 0; i < 3; ++i) {
        const float* p = base + i * LW;
        const float4 a = *(const float4*)p;
        const float4 b = *(const float4*)(p + 4);
        const float2 e = *(const float2*)(p + 8);
        r[i][0] = a.x; r[i][1] = a.y; r[i][2] = a.z; r[i][3] = a.w;
        r[i][4] = b.x; r[i][5] = b.y; r[i][6] = b.z; r[i][7] = b.w;
        r[i][8] = e.x; r[i][9] = e.y;
    }

    float cs[10], cq[10], cm[10];
#pragma unroll
    for (int c = 0; c < 10; ++c) {
        cs[c] = r[0][c] + r[1][c] + r[2][c];
        cq[c] = fmaf(r[0][c], r[0][c], fmaf(r[1][c], r[1][c], r[2][c] * r[2][c]));
        cm[c] = fmaxf(r[0][c], fmaxf(r[1][c], r[2][c]));   // -> v_max3
    }

    float s05 = 0.f, s67 = 0.f;
#pragma unroll
    for (int k = 0; k < 8; ++k) {
        const float ctr  = r[1][k + 1];
        const float sum  = cs[k] + cs[k + 1] + cs[k + 2];
        const float ss   = cq[k] + cq[k + 1] + cq[k + 2];
        const float wmax = fmaxf(cm[k], fmaxf(cm[k + 1], cm[k + 2]));

        const float bv = count9(r[0][k]     - ctr, r[0][k + 1] - ctr,
                                r[0][k + 2] - ctr, r[1][k]     - ctr,
                                r[1][k + 2] - ctr, r[2][k]     - ctr,
                                r[2][k + 1] - ctr, r[2][k + 2] - ctr);

        const float var9 = fmaf(sum, -sum, 9.f * ss);                // 81*var
        const float sd9  = __builtin_amdgcn_sqrtf(fmaxf(var9, 0.f)); // 9*std
        const float nf   = fmaf(sum, -1.f / 2295.f, bv * (1.f / 255.f));
        const float bn   = fmaf(nf, fmaf(sd9, 1.f / 9.f, -wmax), wmax);

        if (k < 6) s05 += bn;
        else       s67 += bn;
    }
    return s05 + (full ? s67 : 0.f);
}

// One block = one plane, 1024 blocks x 256 thr = 4 blocks/CU, exactly one
// round, SINGLE dispatch. 8 pipelined chunks (16x7 + 14 output rows),
// double-buffered LDS, reg-staged prefetch. Plain (256): every min-waves
// hint this session (R3/R5/R8/R15) spilled or starved the body.
__global__ __launch_bounds__(256) void bp_kernel(const float* __restrict__ x,
                                                 float* __restrict__ out) {
    __shared__ float buf[2][BSZ];
    __shared__ float wred[4];

    const int t     = threadIdx.x;
    const int plane = blockIdx.x;
    const float4* s4 = (const float4*)(x + (size_t)plane * (H * W));

    // ---- prologue: stage chunk 0 (18 rows = 576 float4) into buf0 ----
    {
        float4 g0 = s4[t], g1 = s4[t + 256], g2;
        if (t < 64) g2 = s4[t + 512];
        float4* b4 = (float4*)buf[0];
        b4[t] = g0; b4[t + 256] = g1;
        if (t < 64) b4[t + 512] = g2;
    }
    __syncthreads();

    const int y  = t >> 4;        // group row within chunk (0..15)
    const int xq = t & 15;        // 8-px strip
    const bool full = (xq != 15); // WO = 126 = 15*8 + 6
    const int goff = y * LW + xq * 8;

    float acc = 0.f;

#pragma unroll 2
    for (int c = 0; c < 8; ++c) {
        float4 g0, g1, g2;
        const bool pre   = (c < 7);
        const bool third = (c < 6);          // chunk 7 stages only 16 rows
        if (pre) {
            const int base = (c + 1) * 512;
            g0 = s4[base + t];
            g1 = s4[base + t + 256];
            if (third && t < 64) g2 = s4[base + t + 512];
        }

        if (c < 7 || y < 14)                 // chunk 7: 14 output rows
            acc += grp8(&buf[c & 1][goff], full);

        if (pre) {
            float4* d4 = (float4*)buf[(c + 1) & 1];
            d4[t] = g0; d4[t + 256] = g1;    // vmcnt wait lands here
            if (third && t < 64) d4[t + 512] = g2;
        }
        __syncthreads();
    }

    // ---- reduction: 4 waves -> out[plane] ----
#pragma unroll
    for (int off = 32; off > 0; off >>= 1)
        acc += __shfl_down(acc, off, 64);
    if ((t & 63) == 0) wred[t >> 6] = acc;
    __syncthreads();
    if (t == 0)
        out[plane] = (wred[0] + wred[1] + wred[2] + wred[3]) * (1.f / NPIX);
}

extern "C" void kernel_launch(void* const* d_in, const int* in_sizes, int n_in,
                              void* d_out, int out_size, void* d_ws, size_t ws_size,
                              hipStream_t stream) {
    const float* x = (const float*)d_in[0];
    float* out = (float*)d_out;
    bp_kernel<<<dim3(16 * 64), dim3(256), 0, stream>>>(x, out);
}

// Round 19
// 28.131 us; speedup vs baseline: 1.1562x; 1.1562x over previous
//
#include <hip/hip_runtime.h>

#define H     128
#define W     128
#define HO    126
#define WO    126
#define NPIX  (HO * WO)      // 15876
#define LW    128            // LDS row stride
#define BROWS 18             // staged rows per chunk buffer
#define BSZ   (BROWS * LW + 8)

// |d|-sum, threshold, tap count: 27 hand-scheduled VALU instrs.
// (Asm ONLY here: compiler's compare/count codegen is fat; its FP-chain
// scheduling elsewhere is good -- R17 showed asm epi/max3 regresses.)
// Center tap contributes (0 >= thr) === (0 >= sad); cndmask inits cnt.
static __device__ __forceinline__ float count9(float d0, float d1, float d2, float d3,
                                               float d4, float d5, float d6, float d7) {
    float t0, t1, t2, t3, t4, t5, sad, thr, cnt, bvf;
    asm("v_add_f32 %[t0], |%[d0]|, |%[d1]|\n\t"
        "v_add_f32 %[t1], |%[d2]|, |%[d3]|\n\t"
        "v_add_f32 %[t2], |%[d4]|, |%[d5]|\n\t"
        "v_add_f32 %[t3], |%[d6]|, |%[d7]|\n\t"
        "v_add_f32 %[t4], %[t0], %[t1]\n\t"
        "v_add_f32 %[t5], %[t2], %[t3]\n\t"
        "v_add_f32 %[sad], %[t4], %[t5]\n\t"
        "v_mul_f32 %[thr], 0x3de38e39, %[sad]\n\t"   // * 1/9
        "v_cmp_ge_f32 vcc, 0, %[sad]\n\t"            // center tap
        "v_cndmask_b32 %[cnt], 0, 1, vcc\n\t"
        "v_cmp_ge_f32 vcc, %[d0], %[thr]\n\t"
        "v_addc_co_u32 %[cnt], vcc, 0, %[cnt], vcc\n\t"
        "v_cmp_ge_f32 vcc, %[d1], %[thr]\n\t"
        "v_addc_co_u32 %[cnt], vcc, 0, %[cnt], vcc\n\t"
        "v_cmp_ge_f32 vcc, %[d2], %[thr]\n\t"
        "v_addc_co_u32 %[cnt], vcc, 0, %[cnt], vcc\n\t"
        "v_cmp_ge_f32 vcc, %[d3], %[thr]\n\t"
        "v_addc_co_u32 %[cnt], vcc, 0, %[cnt], vcc\n\t"
        "v_cmp_ge_f32 vcc, %[d4], %[thr]\n\t"
        "v_addc_co_u32 %[cnt], vcc, 0, %[cnt], vcc\n\t"
        "v_cmp_ge_f32 vcc, %[d5], %[thr]\n\t"
        "v_addc_co_u32 %[cnt], vcc, 0, %[cnt], vcc\n\t"
        "v_cmp_ge_f32 vcc, %[d6], %[thr]\n\t"
        "v_addc_co_u32 %[cnt], vcc, 0, %[cnt], vcc\n\t"
        "v_cmp_ge_f32 vcc, %[d7], %[thr]\n\t"
        "v_addc_co_u32 %[cnt], vcc, 0, %[cnt], vcc\n\t"
        "v_cvt_f32_u32 %[bvf], %[cnt]"
        : [t0]"=&v"(t0), [t1]"=&v"(t1), [t2]"=&v"(t2), [t3]"=&v"(t3),
          [t4]"=&v"(t4), [t5]"=&v"(t5), [sad]"=&v"(sad), [thr]"=&v"(thr),
          [cnt]"=&v"(cnt), [bvf]"=v"(bvf)
        : [d0]"v"(d0), [d1]"v"(d1), [d2]"v"(d2), [d3]"v"(d3),
          [d4]"v"(d4), [d5]"v"(d5), [d6]"v"(d6), [d7]"v"(d7)
        : "vcc");
    return bvf;
}

// 8-px group: rows y..y+2, cols x0..x0+9. px 0..5 always valid; 6,7 iff full.
static __device__ __forceinline__ float grp8(const float* __restrict__ base, bool full) {
    float r[3][10];
#pragma unroll
    for (int i = 0; i < 3; ++i) {
        const float* p = base + i * LW;
        const float4 a = *(const float4*)p;
        const float4 b = *(const float4*)(p + 4);
        const float2 e = *(const float2*)(p + 8);
        r[i][0] = a.x; r[i][1] = a.y; r[i][2] = a.z; r[i][3] = a.w;
        r[i][4] = b.x; r[i][5] = b.y; r[i][6] = b.z; r[i][7] = b.w;
        r[i][8] = e.x; r[i][9] = e.y;
    }

    float cs[10], cq[10], cm[10];
#pragma unroll
    for (int c = 0; c < 10; ++c) {
        cs[c] = r[0][c] + r[1][c] + r[2][c];
        cq[c] = fmaf(r[0][c], r[0][c], fmaf(r[1][c], r[1][c], r[2][c] * r[2][c]));
        cm[c] = fmaxf(r[0][c], fmaxf(r[1][c], r[2][c]));   // -> v_max3
    }

    float s05 = 0.f, s67 = 0.f;
#pragma unroll
    for (int k = 0; k < 8; ++k) {
        const float ctr  = r[1][k + 1];
        const float sum  = cs[k] + cs[k + 1] + cs[k + 2];
        const float ss   = cq[k] + cq[k + 1] + cq[k + 2];
        const float wmax = fmaxf(cm[k], fmaxf(cm[k + 1], cm[k + 2]));

        const float bv = count9(r[0][k]     - ctr, r[0][k + 1] - ctr,
                                r[0][k + 2] - ctr, r[1][k]     - ctr,
                                r[1][k + 2] - ctr, r[2][k]     - ctr,
                                r[2][k + 1] - ctr, r[2][k + 2] - ctr);

        const float var9 = fmaf(sum, -sum, 9.f * ss);                // 81*var
        const float sd9  = __builtin_amdgcn_sqrtf(fmaxf(var9, 0.f)); // 9*std
        const float nf   = fmaf(sum, -1.f / 2295.f, bv * (1.f / 255.f));
        const float bn   = fmaf(nf, fmaf(sd9, 1.f / 9.f, -wmax), wmax);

        if (k < 6) s05 += bn;
        else       s67 += bn;
    }
    return s05 + (full ? s67 : 0.f);
}

// One block = one 63-row half-plane. 2048 blocks x 256 thr. 4 fully-unrolled
// pipelined chunks (16,16,16,15 output rows), double-buffered LDS, reg-staged
// prefetch. Plain (256): every min-waves hint this session spilled or starved.
__global__ __launch_bounds__(256) void bp_kernel(const float* __restrict__ x,
                                                 float* __restrict__ ws) {
    __shared__ float buf[2][BSZ];
    __shared__ float wred[4];

    const int t     = threadIdx.x;
    const int bid   = blockIdx.x;
    const int plane = bid >> 1;
    const int half  = bid & 1;
    const float4* s4 = (const float4*)(x + (size_t)plane * (H * W)) + (63 * half) * 32;

    // ---- prologue: stage chunk 0 (18 rows = 576 float4) into buf0 ----
    {
        float4 g0 = s4[t], g1 = s4[t + 256], g2;
        if (t < 64) g2 = s4[t + 512];
        float4* b4 = (float4*)buf[0];
        b4[t] = g0; b4[t + 256] = g1;
        if (t < 64) b4[t + 512] = g2;
    }
    __syncthreads();

    const int y  = t >> 4;        // group row within chunk (0..15)
    const int xq = t & 15;        // 8-px strip
    const bool full = (xq != 15); // WO = 126 = 15*8 + 6
    const int goff = y * LW + xq * 8;

    float acc = 0.f;

#pragma unroll
    for (int c = 0; c < 4; ++c) {
        float4 g0, g1, g2;
        const bool pre = (c < 3);
        const int  nthird = (c == 2) ? 32 : 64;   // chunk 3 stages 17 rows
        if (pre) {
            const int base = (c + 1) * 512;
            g0 = s4[base + t];
            g1 = s4[base + t + 256];
            if (t < nthird) g2 = s4[base + t + 512];
        }

        if (c < 3 || y < 15)                      // chunk 3: 15 output rows
            acc += grp8(&buf[c & 1][goff], full);

        if (pre) {
            float4* d4 = (float4*)buf[(c + 1) & 1];
            d4[t] = g0; d4[t + 256] = g1;         // vmcnt wait lands here
            if (t < nthird) d4[t + 512] = g2;
        }
        __syncthreads();
    }

    // ---- reduction: 4 waves -> ws[bid] ----
#pragma unroll
    for (int off = 32; off > 0; off >>= 1)
        acc += __shfl_down(acc, off, 64);
    if ((t & 63) == 0) wred[t >> 6] = acc;
    __syncthreads();
    if (t == 0)
        ws[bid] = wred[0] + wred[1] + wred[2] + wred[3];
}

// fold the two half-plane partials -> mean
__global__ __launch_bounds__(1024) void combine(const float* __restrict__ ws,
                                                float* __restrict__ out) {
    const int p = threadIdx.x;
    out[p] = (ws[2 * p] + ws[2 * p + 1]) * (1.f / NPIX);
}

extern "C" void kernel_launch(void* const* d_in, const int* in_sizes, int n_in,
                              void* d_out, int out_size, void* d_ws, size_t ws_size,
                              hipStream_t stream) {
    const float* x = (const float*)d_in[0];
    float* out = (float*)d_out;
    float* ws  = (float*)d_ws;
    bp_kernel<<<dim3(2048), dim3(256), 0, stream>>>(x, ws);
    combine<<<dim3(1), dim3(1024), 0, stream>>>(ws, out);
}